// Round 1
// baseline (1798.242 us; speedup 1.0000x reference)
//
#include <hip/hip_runtime.h>
#include <stdint.h>
#include <math.h>

#define B_   32
#define N_   1024
#define U_   32
#define E_   64
#define LIT_ 12
#define SEM_ 16
#define GBN  64   // 2 graphs * 32 batch

// ---------------- workspace layout (bytes) ----------------
// xproj: 2*32*1024*96*4 = 25165824
// t    : 2*32*1024*64*4 = 16777216
// e    : 2*32*1024*64*4 = 16777216
// outws: 2*32*64*4      = 16384
// cfg8 : 2*32*1024*1024 = 67108864
#define XPROJ_OFF 0ULL
#define T_OFF     25165824ULL
#define E_OFF     41943040ULL
#define OW_OFF    58720256ULL
#define C8_OFF    58736640ULL
#define WS_MIN    58736640ULL
#define WS_FULL   125845504ULL

// ---------- cfg int32 -> u8 (packed) ----------
__global__ __launch_bounds__(256) void k_cfg_u8(const int* __restrict__ c1,
                                                const int* __restrict__ c2,
                                                uint32_t* __restrict__ out) {
    long long i = (long long)blockIdx.x * blockDim.x + threadIdx.x; // int4 index
    const long long per = (long long)B_ * N_ * N_ / 4;              // 8388608
    const int4* src = (i < per) ? (const int4*)c1 : (const int4*)c2;
    long long j = (i < per) ? i : i - per;
    int4 v = src[j];
    uint32_t p = (uint32_t)(v.x & 1) | ((uint32_t)(v.y & 1) << 8) |
                 ((uint32_t)(v.z & 1) << 16) | ((uint32_t)(v.w & 1) << 24);
    out[i] = p;
}

// ---------- literal path + GRU input projection ----------
__global__ __launch_bounds__(64) void k_pre(
    const float* __restrict__ lit1, const float* __restrict__ sem1,
    const float* __restrict__ lit2, const float* __restrict__ sem2,
    const float* __restrict__ Win1, const float* __restrict__ bin1,
    const float* __restrict__ Wout1, const float* __restrict__ bout1,
    const float* __restrict__ gk1, const float* __restrict__ gb1,
    const float* __restrict__ Win2, const float* __restrict__ bin2,
    const float* __restrict__ Wout2, const float* __restrict__ bout2,
    const float* __restrict__ gk2, const float* __restrict__ gb2,
    float* __restrict__ ebuf, float* __restrict__ xproj)
{
    __shared__ float lit_ls[LIT_];
    __shared__ float sem_ls[SEM_];
    __shared__ float mid_ls[E_];
    const int tid = threadIdx.x;
    const long long rowbase = (long long)blockIdx.x * 8;
    for (int rr = 0; rr < 8; ++rr) {
        long long row = rowbase + rr;              // (g*32+b)*1024 + n
        int g = (int)(row >> 15);
        long long nIdx = row & 32767;              // b*1024+n
        const float* lit  = g ? lit2  : lit1;
        const float* sem  = g ? sem2  : sem1;
        const float* Win  = g ? Win2  : Win1;
        const float* bin  = g ? bin2  : bin1;
        const float* Wout = g ? Wout2 : Wout1;
        const float* bout = g ? bout2 : bout1;
        const float* gk   = g ? gk2   : gk1;
        const float* gbp  = g ? gb2   : gb1;

        if (tid < LIT_) lit_ls[tid] = lit[nIdx * LIT_ + tid];
        if (tid < SEM_) sem_ls[tid] = sem[nIdx * SEM_ + tid];
        __syncthreads();

        // mid = relu(lit@Win + bin)
        float acc = bin[tid];
        #pragma unroll
        for (int k = 0; k < LIT_; ++k) acc += lit_ls[k] * Win[k * E_ + tid];
        mid_ls[tid] = fmaxf(acc, 0.f);
        __syncthreads();

        if (tid < U_) {
            float a = bout[tid];
            #pragma unroll
            for (int k = 0; k < E_; ++k) a += mid_ls[k] * Wout[k * U_ + tid];
            ebuf[row * E_ + tid] = fmaxf(a, 0.f);   // literal half (>=0, relu idempotent)
        }
        // xproj = sem@gk + b_in  (cols tid and 64+tid for tid<32)
        {
            float a = gbp[tid];
            #pragma unroll
            for (int k = 0; k < SEM_; ++k) a += sem_ls[k] * gk[k * 96 + tid];
            xproj[row * 96 + tid] = a;
        }
        if (tid < 32) {
            int j = 64 + tid;
            float a = gbp[j];
            #pragma unroll
            for (int k = 0; k < SEM_; ++k) a += sem_ls[k] * gk[k * 96 + j];
            xproj[row * 96 + j] = a;
        }
        __syncthreads();
    }
}

// ---------- GRU recurrence (1 block per (g,b)) ----------
__global__ __launch_bounds__(128) void k_gru(
    const float* __restrict__ grk1, const float* __restrict__ gb1,
    const float* __restrict__ grk2, const float* __restrict__ gb2,
    const float* __restrict__ xproj, float* __restrict__ ebuf)
{
    __shared__ __align__(16) float h_ls[U_];
    __shared__ float rec_ls[96];
    __shared__ float x_ls[96];
    const int gb_i = blockIdx.x;          // 0..63
    const int g = gb_i >> 5;
    const float* grk = g ? grk2 : grk1;
    const float* gbp = g ? gb2 : gb1;
    const int j = threadIdx.x;

    float wcol[U_];
    float brec = 0.f;
    if (j < 96) {
        #pragma unroll
        for (int k = 0; k < U_; ++k) wcol[k] = grk[k * 96 + j];
        brec = gbp[96 + j];
    } else {
        #pragma unroll
        for (int k = 0; k < U_; ++k) wcol[k] = 0.f;
    }
    if (j < U_) h_ls[j] = 0.f;
    float hreg = 0.f;
    const float* xp = xproj + (long long)gb_i * N_ * 96;
    float* eb = ebuf + (long long)gb_i * N_ * E_;
    float xv = (j < 96) ? xp[j] : 0.f;
    __syncthreads();

    for (int t = 0; t < N_; ++t) {
        float xnext = 0.f;
        if (t + 1 < N_ && j < 96) xnext = xp[(long long)(t + 1) * 96 + j];
        // rec = h @ Wr + b_rec
        float rec = brec;
        const float4* h4 = (const float4*)h_ls;
        #pragma unroll
        for (int q = 0; q < 8; ++q) {
            float4 hv = h4[q];
            rec += hv.x * wcol[4*q] + hv.y * wcol[4*q+1] +
                   hv.z * wcol[4*q+2] + hv.w * wcol[4*q+3];
        }
        if (j < 96) { rec_ls[j] = rec; x_ls[j] = xv; }
        __syncthreads();
        if (j < U_) {
            float z = 1.f / (1.f + __expf(-(x_ls[j]      + rec_ls[j])));
            float r = 1.f / (1.f + __expf(-(x_ls[32 + j] + rec_ls[32 + j])));
            float hh = tanhf(x_ls[64 + j] + r * rec_ls[64 + j]);
            float hn = z * hreg + (1.f - z) * hh;
            hreg = hn;
            h_ls[j] = hn;
            eb[(long long)t * E_ + 32 + j] = fmaxf(hn, 0.f);  // relu at graph entry
        }
        __syncthreads();
        xv = xnext;
    }
}

// ---------- message passing: t = cfg @ e  (128 rows x 64 cols per block) ----------
template <int USE_U8>
__global__ __launch_bounds__(256) void k_msg(
    const uint8_t* __restrict__ cfg8,
    const int* __restrict__ cfgi1, const int* __restrict__ cfgi2,
    const float* __restrict__ ebuf, float* __restrict__ tbuf)
{
    __shared__ float cfgf[128][65];
    __shared__ float els[64][64];
    const int blk = blockIdx.x;          // 512
    const int gb_i = blk >> 3;
    const int rg = blk & 7;
    const int g = gb_i >> 5;
    const int b = gb_i & 31;
    const int n0 = rg * 128;
    const int tid = threadIdx.x;
    const int tx = tid & 7, ty = tid >> 3;

    float acc[4][8];
    #pragma unroll
    for (int i = 0; i < 4; ++i)
        #pragma unroll
        for (int c = 0; c < 8; ++c) acc[i][c] = 0.f;

    const float* ebase = ebuf + (long long)gb_i * N_ * E_;
    const int row = tid >> 1, half = tid & 1;

    for (int m0 = 0; m0 < N_; m0 += 64) {
        // stage e[m0:m0+64, 0:64]
        {
            const float4* src = (const float4*)(ebase + (long long)m0 * E_);
            float4* dst = (float4*)(&els[0][0]);
            #pragma unroll
            for (int k = 0; k < 4; ++k) dst[tid + 256 * k] = src[tid + 256 * k];
        }
        // stage cfg[n0:n0+128, m0:m0+64] as f32
        if (USE_U8) {
            const uint8_t* cp = cfg8 + ((long long)gb_i * N_ + n0 + row) * N_ + m0 + half * 32;
            uint4 v0 = *(const uint4*)cp;
            uint4 v1 = *(const uint4*)(cp + 16);
            uint32_t wv[8] = {v0.x, v0.y, v0.z, v0.w, v1.x, v1.y, v1.z, v1.w};
            #pragma unroll
            for (int q = 0; q < 8; ++q)
                #pragma unroll
                for (int s = 0; s < 4; ++s)
                    cfgf[row][half * 32 + q * 4 + s] = (float)((wv[q] >> (8 * s)) & 0xffu);
        } else {
            const int* cp = (g ? cfgi2 : cfgi1) + ((long long)b * N_ + n0 + row) * N_ + m0 + half * 32;
            #pragma unroll
            for (int q = 0; q < 8; ++q) {
                int4 v = ((const int4*)cp)[q];
                cfgf[row][half * 32 + q * 4 + 0] = (float)v.x;
                cfgf[row][half * 32 + q * 4 + 1] = (float)v.y;
                cfgf[row][half * 32 + q * 4 + 2] = (float)v.z;
                cfgf[row][half * 32 + q * 4 + 3] = (float)v.w;
            }
        }
        __syncthreads();

        #pragma unroll 4
        for (int mm = 0; mm < 64; ++mm) {
            float4 e0 = *(const float4*)&els[mm][tx * 8];
            float4 e1 = *(const float4*)&els[mm][tx * 8 + 4];
            #pragma unroll
            for (int i = 0; i < 4; ++i) {
                float c = cfgf[ty + 32 * i][mm];
                acc[i][0] += c * e0.x; acc[i][1] += c * e0.y;
                acc[i][2] += c * e0.z; acc[i][3] += c * e0.w;
                acc[i][4] += c * e1.x; acc[i][5] += c * e1.y;
                acc[i][6] += c * e1.z; acc[i][7] += c * e1.w;
            }
        }
        __syncthreads();
    }

    float* tb = tbuf + (long long)gb_i * N_ * E_;
    #pragma unroll
    for (int i = 0; i < 4; ++i) {
        int r = n0 + ty + 32 * i;
        float4 o0 = {acc[i][0], acc[i][1], acc[i][2], acc[i][3]};
        float4 o1 = {acc[i][4], acc[i][5], acc[i][6], acc[i][7]};
        *(float4*)&tb[(long long)r * E_ + tx * 8] = o0;
        *(float4*)&tb[(long long)r * E_ + tx * 8 + 4] = o1;
    }
}

// ---------- 2-layer MLP + tanh residual update (lane = row, scalar weights) ----------
__global__ __launch_bounds__(64) void k_mlp(
    const float* __restrict__ tbuf, float* __restrict__ ebuf,
    const float* __restrict__ mlpW, const float* __restrict__ mlpb)
{
    __shared__ float tls[64][65];
    __shared__ float mls[64][65];
    const int tid = threadIdx.x;
    const long long r0 = (long long)blockIdx.x * 64;

    // stage 64 rows of t (coalesced)
    {
        const float4* src = (const float4*)(tbuf + r0 * E_);
        #pragma unroll
        for (int i = 0; i < 16; ++i) {
            int f4 = tid + 64 * i;
            float4 v = src[f4];
            int row = f4 >> 4, col = (f4 & 15) << 2;
            tls[row][col] = v.x; tls[row][col + 1] = v.y;
            tls[row][col + 2] = v.z; tls[row][col + 3] = v.w;
        }
    }
    __syncthreads();

    // layer 1: mid = relu(t @ W0 + b0)   (W uniform -> scalar loads)
    for (int dc = 0; dc < 8; ++dc) {
        float a[8];
        #pragma unroll
        for (int c = 0; c < 8; ++c) a[c] = mlpb[dc * 8 + c];
        #pragma unroll 8
        for (int k = 0; k < 64; ++k) {
            float tv = tls[tid][k];
            #pragma unroll
            for (int c = 0; c < 8; ++c) a[c] += tv * mlpW[k * 64 + dc * 8 + c];
        }
        #pragma unroll
        for (int c = 0; c < 8; ++c) mls[tid][dc * 8 + c] = fmaxf(a[c], 0.f);
    }
    // layer 2: t3 = relu(mid @ W1 + b1) -> overwrite tls row
    for (int dc = 0; dc < 8; ++dc) {
        float a[8];
        #pragma unroll
        for (int c = 0; c < 8; ++c) a[c] = mlpb[64 + dc * 8 + c];
        #pragma unroll 8
        for (int k = 0; k < 64; ++k) {
            float tv = mls[tid][k];
            #pragma unroll
            for (int c = 0; c < 8; ++c) a[c] += tv * mlpW[4096 + k * 64 + dc * 8 + c];
        }
        #pragma unroll
        for (int c = 0; c < 8; ++c) tls[tid][dc * 8 + c] = fmaxf(a[c], 0.f);
    }
    __syncthreads();

    // e = tanh(e + t3) (coalesced)
    {
        float4* eb = (float4*)(ebuf + r0 * E_);
        #pragma unroll
        for (int i = 0; i < 16; ++i) {
            int f4 = tid + 64 * i;
            int row = f4 >> 4, col = (f4 & 15) << 2;
            float4 ev = eb[f4];
            float4 o;
            o.x = tanhf(ev.x + tls[row][col]);
            o.y = tanhf(ev.y + tls[row][col + 1]);
            o.z = tanhf(ev.z + tls[row][col + 2]);
            o.w = tanhf(ev.w + tls[row][col + 3]);
            eb[f4] = o;
        }
    }
}

// ---------- node-sum + output projection ----------
__global__ __launch_bounds__(64) void k_out(const float* __restrict__ ebuf,
                                            const float* __restrict__ wOut,
                                            const float* __restrict__ bOut,
                                            float* __restrict__ outws)
{
    __shared__ float mid[E_];
    const int gb_i = blockIdx.x;
    const int tid = threadIdx.x;
    const float* eb = ebuf + (long long)gb_i * N_ * E_;
    float s = 0.f;
    for (int n = 0; n < N_; ++n) s += eb[(long long)n * E_ + tid];
    mid[tid] = s;
    __syncthreads();
    float a = bOut[tid];
    #pragma unroll 8
    for (int k = 0; k < E_; ++k) a += mid[k] * wOut[k * E_ + tid];
    outws[gb_i * E_ + tid] = a;
}

// ---------- cosine -> label ----------
__global__ __launch_bounds__(64) void k_cos(const float* __restrict__ outws,
                                            float* __restrict__ dout)
{
    const int b = blockIdx.x, d = threadIdx.x;
    float a = outws[b * E_ + d];
    float c = outws[(32 + b) * E_ + d];
    float s1 = a * a, s2 = c * c, s3 = a * c;
    #pragma unroll
    for (int m = 32; m > 0; m >>= 1) {
        s1 += __shfl_xor(s1, m);
        s2 += __shfl_xor(s2, m);
        s3 += __shfl_xor(s3, m);
    }
    if (d == 0) {
        float n1 = sqrtf(fmaxf(s1, 1e-12f));
        float n2 = sqrtf(fmaxf(s2, 1e-12f));
        dout[b] = 0.5f * (s3 / (n1 * n2) + 1.0f);
    }
}

extern "C" void kernel_launch(void* const* d_in, const int* in_sizes, int n_in,
                              void* d_out, int out_size, void* d_ws, size_t ws_size,
                              hipStream_t stream) {
    const int*   CFG1 = (const int*)d_in[0];
    const float* LIT1 = (const float*)d_in[2];
    const float* SEM1 = (const float*)d_in[3];
    const int*   CFG2 = (const int*)d_in[4];
    const float* LIT2 = (const float*)d_in[6];
    const float* SEM2 = (const float*)d_in[7];
    const float* d1_Win  = (const float*)d_in[8];
    const float* d1_bin  = (const float*)d_in[9];
    const float* d1_Wout = (const float*)d_in[10];
    const float* d1_bout = (const float*)d_in[11];
    const float* d1_gk   = (const float*)d_in[12];
    const float* d1_grk  = (const float*)d_in[13];
    const float* d1_gb   = (const float*)d_in[14];
    const float* d2_Win  = (const float*)d_in[15];
    const float* d2_bin  = (const float*)d_in[16];
    const float* d2_Wout = (const float*)d_in[17];
    const float* d2_bout = (const float*)d_in[18];
    const float* d2_gk   = (const float*)d_in[19];
    const float* d2_grk  = (const float*)d_in[20];
    const float* d2_gb   = (const float*)d_in[21];
    const float* mlpW = (const float*)d_in[22];
    const float* mlpb = (const float*)d_in[23];
    const float* wOut = (const float*)d_in[24];
    const float* bOut = (const float*)d_in[25];

    char* ws = (char*)d_ws;
    float*    xproj = (float*)(ws + XPROJ_OFF);
    float*    tbuf  = (float*)(ws + T_OFF);
    float*    ebuf  = (float*)(ws + E_OFF);
    float*    outws = (float*)(ws + OW_OFF);
    uint32_t* cfg8  = (uint32_t*)(ws + C8_OFF);

    if (ws_size < WS_MIN) return;
    const bool use_u8 = (ws_size >= WS_FULL);

    if (use_u8)
        k_cfg_u8<<<65536, 256, 0, stream>>>(CFG1, CFG2, cfg8);

    k_pre<<<8192, 64, 0, stream>>>(LIT1, SEM1, LIT2, SEM2,
                                   d1_Win, d1_bin, d1_Wout, d1_bout, d1_gk, d1_gb,
                                   d2_Win, d2_bin, d2_Wout, d2_bout, d2_gk, d2_gb,
                                   ebuf, xproj);

    k_gru<<<64, 128, 0, stream>>>(d1_grk, d1_gb, d2_grk, d2_gb, xproj, ebuf);

    for (int it = 0; it < 5; ++it) {
        if (use_u8)
            k_msg<1><<<512, 256, 0, stream>>>((const uint8_t*)cfg8, CFG1, CFG2, ebuf, tbuf);
        else
            k_msg<0><<<512, 256, 0, stream>>>((const uint8_t*)cfg8, CFG1, CFG2, ebuf, tbuf);
        k_mlp<<<1024, 64, 0, stream>>>(tbuf, ebuf, mlpW, mlpb);
    }

    k_out<<<GBN, 64, 0, stream>>>(ebuf, wOut, bOut, outws);
    k_cos<<<32, 64, 0, stream>>>(outws, (float*)d_out);
}

// Round 2
// 1469.908 us; speedup vs baseline: 1.2234x; 1.2234x over previous
//
#include <hip/hip_runtime.h>
#include <stdint.h>
#include <math.h>

#define B_   32
#define N_   1024
#define U_   32
#define E_   64
#define LIT_ 12
#define SEM_ 16
#define GBN  64   // 2 graphs * 32 batch

// ---------------- workspace layout (bytes) ----------------
#define XPROJ_OFF 0ULL
#define T_OFF     25165824ULL
#define E_OFF     41943040ULL
#define OW_OFF    58720256ULL
#define C8_OFF    58736640ULL
#define WS_MIN    58736640ULL
#define WS_FULL   125845504ULL

__device__ __forceinline__ float rdlane(float v, int k) {
    return __int_as_float(__builtin_amdgcn_readlane(__float_as_int(v), k));
}

// ---------- cfg int32 -> u8 (packed) ----------
__global__ __launch_bounds__(256) void k_cfg_u8(const int* __restrict__ c1,
                                                const int* __restrict__ c2,
                                                uint32_t* __restrict__ out) {
    long long i = (long long)blockIdx.x * blockDim.x + threadIdx.x; // int4 index
    const long long per = (long long)B_ * N_ * N_ / 4;              // 8388608
    const int4* src = (i < per) ? (const int4*)c1 : (const int4*)c2;
    long long j = (i < per) ? i : i - per;
    int4 v = src[j];
    uint32_t p = (uint32_t)(v.x & 1) | ((uint32_t)(v.y & 1) << 8) |
                 ((uint32_t)(v.z & 1) << 16) | ((uint32_t)(v.w & 1) << 24);
    out[i] = p;
}

// ---------- literal path + GRU input projection ----------
__global__ __launch_bounds__(64) void k_pre(
    const float* __restrict__ lit1, const float* __restrict__ sem1,
    const float* __restrict__ lit2, const float* __restrict__ sem2,
    const float* __restrict__ Win1, const float* __restrict__ bin1,
    const float* __restrict__ Wout1, const float* __restrict__ bout1,
    const float* __restrict__ gk1, const float* __restrict__ gb1,
    const float* __restrict__ Win2, const float* __restrict__ bin2,
    const float* __restrict__ Wout2, const float* __restrict__ bout2,
    const float* __restrict__ gk2, const float* __restrict__ gb2,
    float* __restrict__ ebuf, float* __restrict__ xproj)
{
    __shared__ float lit_ls[LIT_];
    __shared__ float sem_ls[SEM_];
    __shared__ float mid_ls[E_];
    const int tid = threadIdx.x;
    const long long rowbase = (long long)blockIdx.x * 8;
    for (int rr = 0; rr < 8; ++rr) {
        long long row = rowbase + rr;              // (g*32+b)*1024 + n
        int g = (int)(row >> 15);
        long long nIdx = row & 32767;              // b*1024+n
        const float* lit  = g ? lit2  : lit1;
        const float* sem  = g ? sem2  : sem1;
        const float* Win  = g ? Win2  : Win1;
        const float* bin  = g ? bin2  : bin1;
        const float* Wout = g ? Wout2 : Wout1;
        const float* bout = g ? bout2 : bout1;
        const float* gk   = g ? gk2   : gk1;
        const float* gbp  = g ? gb2   : gb1;

        if (tid < LIT_) lit_ls[tid] = lit[nIdx * LIT_ + tid];
        if (tid < SEM_) sem_ls[tid] = sem[nIdx * SEM_ + tid];
        __syncthreads();

        // mid = relu(lit@Win + bin)
        float acc = bin[tid];
        #pragma unroll
        for (int k = 0; k < LIT_; ++k) acc += lit_ls[k] * Win[k * E_ + tid];
        mid_ls[tid] = fmaxf(acc, 0.f);
        __syncthreads();

        if (tid < U_) {
            float a = bout[tid];
            #pragma unroll
            for (int k = 0; k < E_; ++k) a += mid_ls[k] * Wout[k * U_ + tid];
            ebuf[row * E_ + tid] = fmaxf(a, 0.f);   // literal half
        }
        // xproj = sem@gk + b_in
        {
            float a = gbp[tid];
            #pragma unroll
            for (int k = 0; k < SEM_; ++k) a += sem_ls[k] * gk[k * 96 + tid];
            xproj[row * 96 + tid] = a;
        }
        if (tid < 32) {
            int j = 64 + tid;
            float a = gbp[j];
            #pragma unroll
            for (int k = 0; k < SEM_; ++k) a += sem_ls[k] * gk[k * 96 + j];
            xproj[row * 96 + j] = a;
        }
        __syncthreads();
    }
}

// ---------- GRU recurrence: single wave per (g,b), barrier-free ----------
// lane l owns rec column l (z:0..31, r:32..63); ALL lanes redundantly compute
// the h-column 64+(l&31) so both half-waves derive the identical new h for
// j=l&31 with no post-step broadcast. h[k] broadcast via v_readlane (SGPR).
__global__ __launch_bounds__(64) void k_gru(
    const float* __restrict__ grk1, const float* __restrict__ gb1,
    const float* __restrict__ grk2, const float* __restrict__ gb2,
    const float* __restrict__ xproj, float* __restrict__ ebuf)
{
    const int gb_i = blockIdx.x;          // 0..63
    const int g = gb_i >> 5;
    const float* grk = g ? grk2 : grk1;
    const float* gbp = g ? gb2 : gb1;
    const int l = threadIdx.x;            // 0..63
    const int j = l & 31;

    float wzr[32];                        // Wr[k][l]
    float wh[32];                         // Wr[k][64+j]
    #pragma unroll
    for (int k = 0; k < 32; ++k) {
        wzr[k] = grk[k * 96 + l];
        wh[k]  = grk[k * 96 + 64 + j];
    }
    const float brec0 = gbp[96 + l];
    const float brec1 = gbp[96 + 64 + j];

    const float* xp = xproj + (long long)gb_i * N_ * 96;
    float* eb = ebuf + (long long)gb_i * N_ * E_ + 32;

    float h = 0.f;

    auto STEP = [&](float X0, float X1, int T) {
        float a0 = brec0, a1 = 0.f, a2 = 0.f, a3 = 0.f;
        float b0 = brec1, b1 = 0.f, b2 = 0.f, b3 = 0.f;
        #pragma unroll
        for (int k = 0; k < 32; k += 4) {
            float h0 = rdlane(h, k);
            float h1 = rdlane(h, k + 1);
            float h2 = rdlane(h, k + 2);
            float h3 = rdlane(h, k + 3);
            a0 = fmaf(h0, wzr[k],     a0);  b0 = fmaf(h0, wh[k],     b0);
            a1 = fmaf(h1, wzr[k + 1], a1);  b1 = fmaf(h1, wh[k + 1], b1);
            a2 = fmaf(h2, wzr[k + 2], a2);  b2 = fmaf(h2, wh[k + 2], b2);
            a3 = fmaf(h3, wzr[k + 3], a3);  b3 = fmaf(h3, wh[k + 3], b3);
        }
        float rec0 = (a0 + a1) + (a2 + a3);   // rec[l]      (z | r)
        float rec1 = (b0 + b1) + (b2 + b3);   // rec[64+j]   (h-col, same both halves)
        float s = 1.f / (1.f + __expf(-(X0 + rec0)));  // z (lanes<32) | r (lanes>=32)
        float zv = __shfl(s, j);
        float rv = __shfl(s, j + 32);
        float y  = X1 + rv * rec1;
        float e2 = __expf(2.f * y);
        float hh = 1.f - 2.f / (e2 + 1.f);    // tanh(y)
        float hn = hh + zv * (h - hh);
        h = hn;
        if (l < 32) eb[(long long)(T) * E_ + l] = fmaxf(hn, 0.f);
    };

    // prefetch depth 2 steps
    float x0a = xp[l],       x1a = xp[64 + j];
    float x0b = xp[96 + l],  x1b = xp[96 + 64 + j];

    for (int t = 0; t < N_; t += 2) {
        float nx0a = xp[(long long)(t + 2) * 96 + l];
        float nx1a = xp[(long long)(t + 2) * 96 + 64 + j];
        float nx0b = xp[(long long)(t + 3) * 96 + l];
        float nx1b = xp[(long long)(t + 3) * 96 + 64 + j];
        STEP(x0a, x1a, t);
        STEP(x0b, x1b, t + 1);
        x0a = nx0a; x1a = nx1a; x0b = nx0b; x1b = nx1b;
    }
}

// ---------- message passing: t = cfg @ e  (128 rows x 64 cols per block) ----------
template <int USE_U8>
__global__ __launch_bounds__(256) void k_msg(
    const uint8_t* __restrict__ cfg8,
    const int* __restrict__ cfgi1, const int* __restrict__ cfgi2,
    const float* __restrict__ ebuf, float* __restrict__ tbuf)
{
    __shared__ float cfgf[128][65];
    __shared__ float els[64][64];
    const int blk = blockIdx.x;          // 512
    const int gb_i = blk >> 3;
    const int rg = blk & 7;
    const int g = gb_i >> 5;
    const int b = gb_i & 31;
    const int n0 = rg * 128;
    const int tid = threadIdx.x;
    const int tx = tid & 7, ty = tid >> 3;

    float acc[4][8];
    #pragma unroll
    for (int i = 0; i < 4; ++i)
        #pragma unroll
        for (int c = 0; c < 8; ++c) acc[i][c] = 0.f;

    const float* ebase = ebuf + (long long)gb_i * N_ * E_;
    const int row = tid >> 1, half = tid & 1;

    for (int m0 = 0; m0 < N_; m0 += 64) {
        {
            const float4* src = (const float4*)(ebase + (long long)m0 * E_);
            float4* dst = (float4*)(&els[0][0]);
            #pragma unroll
            for (int k = 0; k < 4; ++k) dst[tid + 256 * k] = src[tid + 256 * k];
        }
        if (USE_U8) {
            const uint8_t* cp = cfg8 + ((long long)gb_i * N_ + n0 + row) * N_ + m0 + half * 32;
            uint4 v0 = *(const uint4*)cp;
            uint4 v1 = *(const uint4*)(cp + 16);
            uint32_t wv[8] = {v0.x, v0.y, v0.z, v0.w, v1.x, v1.y, v1.z, v1.w};
            #pragma unroll
            for (int q = 0; q < 8; ++q)
                #pragma unroll
                for (int s = 0; s < 4; ++s)
                    cfgf[row][half * 32 + q * 4 + s] = (float)((wv[q] >> (8 * s)) & 0xffu);
        } else {
            const int* cp = (g ? cfgi2 : cfgi1) + ((long long)b * N_ + n0 + row) * N_ + m0 + half * 32;
            #pragma unroll
            for (int q = 0; q < 8; ++q) {
                int4 v = ((const int4*)cp)[q];
                cfgf[row][half * 32 + q * 4 + 0] = (float)v.x;
                cfgf[row][half * 32 + q * 4 + 1] = (float)v.y;
                cfgf[row][half * 32 + q * 4 + 2] = (float)v.z;
                cfgf[row][half * 32 + q * 4 + 3] = (float)v.w;
            }
        }
        __syncthreads();

        #pragma unroll 4
        for (int mm = 0; mm < 64; ++mm) {
            float4 e0 = *(const float4*)&els[mm][tx * 8];
            float4 e1 = *(const float4*)&els[mm][tx * 8 + 4];
            #pragma unroll
            for (int i = 0; i < 4; ++i) {
                float c = cfgf[ty + 32 * i][mm];
                acc[i][0] += c * e0.x; acc[i][1] += c * e0.y;
                acc[i][2] += c * e0.z; acc[i][3] += c * e0.w;
                acc[i][4] += c * e1.x; acc[i][5] += c * e1.y;
                acc[i][6] += c * e1.z; acc[i][7] += c * e1.w;
            }
        }
        __syncthreads();
    }

    float* tb = tbuf + (long long)gb_i * N_ * E_;
    #pragma unroll
    for (int i = 0; i < 4; ++i) {
        int r = n0 + ty + 32 * i;
        float4 o0 = {acc[i][0], acc[i][1], acc[i][2], acc[i][3]};
        float4 o1 = {acc[i][4], acc[i][5], acc[i][6], acc[i][7]};
        *(float4*)&tb[(long long)r * E_ + tx * 8] = o0;
        *(float4*)&tb[(long long)r * E_ + tx * 8 + 4] = o1;
    }
}

// ---------- 2-layer MLP + tanh residual update ----------
__global__ __launch_bounds__(64) void k_mlp(
    const float* __restrict__ tbuf, float* __restrict__ ebuf,
    const float* __restrict__ mlpW, const float* __restrict__ mlpb)
{
    __shared__ float tls[64][65];
    __shared__ float mls[64][65];
    const int tid = threadIdx.x;
    const long long r0 = (long long)blockIdx.x * 64;

    {
        const float4* src = (const float4*)(tbuf + r0 * E_);
        #pragma unroll
        for (int i = 0; i < 16; ++i) {
            int f4 = tid + 64 * i;
            float4 v = src[f4];
            int row = f4 >> 4, col = (f4 & 15) << 2;
            tls[row][col] = v.x; tls[row][col + 1] = v.y;
            tls[row][col + 2] = v.z; tls[row][col + 3] = v.w;
        }
    }
    __syncthreads();

    for (int dc = 0; dc < 8; ++dc) {
        float a[8];
        #pragma unroll
        for (int c = 0; c < 8; ++c) a[c] = mlpb[dc * 8 + c];
        #pragma unroll 8
        for (int k = 0; k < 64; ++k) {
            float tv = tls[tid][k];
            #pragma unroll
            for (int c = 0; c < 8; ++c) a[c] += tv * mlpW[k * 64 + dc * 8 + c];
        }
        #pragma unroll
        for (int c = 0; c < 8; ++c) mls[tid][dc * 8 + c] = fmaxf(a[c], 0.f);
    }
    for (int dc = 0; dc < 8; ++dc) {
        float a[8];
        #pragma unroll
        for (int c = 0; c < 8; ++c) a[c] = mlpb[64 + dc * 8 + c];
        #pragma unroll 8
        for (int k = 0; k < 64; ++k) {
            float tv = mls[tid][k];
            #pragma unroll
            for (int c = 0; c < 8; ++c) a[c] += tv * mlpW[4096 + k * 64 + dc * 8 + c];
        }
        #pragma unroll
        for (int c = 0; c < 8; ++c) tls[tid][dc * 8 + c] = fmaxf(a[c], 0.f);
    }
    __syncthreads();

    {
        float4* eb = (float4*)(ebuf + r0 * E_);
        #pragma unroll
        for (int i = 0; i < 16; ++i) {
            int f4 = tid + 64 * i;
            int row = f4 >> 4, col = (f4 & 15) << 2;
            float4 ev = eb[f4];
            float4 o;
            o.x = tanhf(ev.x + tls[row][col]);
            o.y = tanhf(ev.y + tls[row][col + 1]);
            o.z = tanhf(ev.z + tls[row][col + 2]);
            o.w = tanhf(ev.w + tls[row][col + 3]);
            eb[f4] = o;
        }
    }
}

// ---------- node-sum + output projection ----------
__global__ __launch_bounds__(64) void k_out(const float* __restrict__ ebuf,
                                            const float* __restrict__ wOut,
                                            const float* __restrict__ bOut,
                                            float* __restrict__ outws)
{
    __shared__ float mid[E_];
    const int gb_i = blockIdx.x;
    const int tid = threadIdx.x;
    const float* eb = ebuf + (long long)gb_i * N_ * E_;
    float s = 0.f;
    for (int n = 0; n < N_; ++n) s += eb[(long long)n * E_ + tid];
    mid[tid] = s;
    __syncthreads();
    float a = bOut[tid];
    #pragma unroll 8
    for (int k = 0; k < E_; ++k) a += mid[k] * wOut[k * E_ + tid];
    outws[gb_i * E_ + tid] = a;
}

// ---------- cosine -> label ----------
__global__ __launch_bounds__(64) void k_cos(const float* __restrict__ outws,
                                            float* __restrict__ dout)
{
    const int b = blockIdx.x, d = threadIdx.x;
    float a = outws[b * E_ + d];
    float c = outws[(32 + b) * E_ + d];
    float s1 = a * a, s2 = c * c, s3 = a * c;
    #pragma unroll
    for (int m = 32; m > 0; m >>= 1) {
        s1 += __shfl_xor(s1, m);
        s2 += __shfl_xor(s2, m);
        s3 += __shfl_xor(s3, m);
    }
    if (d == 0) {
        float n1 = sqrtf(fmaxf(s1, 1e-12f));
        float n2 = sqrtf(fmaxf(s2, 1e-12f));
        dout[b] = 0.5f * (s3 / (n1 * n2) + 1.0f);
    }
}

extern "C" void kernel_launch(void* const* d_in, const int* in_sizes, int n_in,
                              void* d_out, int out_size, void* d_ws, size_t ws_size,
                              hipStream_t stream) {
    const int*   CFG1 = (const int*)d_in[0];
    const float* LIT1 = (const float*)d_in[2];
    const float* SEM1 = (const float*)d_in[3];
    const int*   CFG2 = (const int*)d_in[4];
    const float* LIT2 = (const float*)d_in[6];
    const float* SEM2 = (const float*)d_in[7];
    const float* d1_Win  = (const float*)d_in[8];
    const float* d1_bin  = (const float*)d_in[9];
    const float* d1_Wout = (const float*)d_in[10];
    const float* d1_bout = (const float*)d_in[11];
    const float* d1_gk   = (const float*)d_in[12];
    const float* d1_grk  = (const float*)d_in[13];
    const float* d1_gb   = (const float*)d_in[14];
    const float* d2_Win  = (const float*)d_in[15];
    const float* d2_bin  = (const float*)d_in[16];
    const float* d2_Wout = (const float*)d_in[17];
    const float* d2_bout = (const float*)d_in[18];
    const float* d2_gk   = (const float*)d_in[19];
    const float* d2_grk  = (const float*)d_in[20];
    const float* d2_gb   = (const float*)d_in[21];
    const float* mlpW = (const float*)d_in[22];
    const float* mlpb = (const float*)d_in[23];
    const float* wOut = (const float*)d_in[24];
    const float* bOut = (const float*)d_in[25];

    char* ws = (char*)d_ws;
    float*    xproj = (float*)(ws + XPROJ_OFF);
    float*    tbuf  = (float*)(ws + T_OFF);
    float*    ebuf  = (float*)(ws + E_OFF);
    float*    outws = (float*)(ws + OW_OFF);
    uint32_t* cfg8  = (uint32_t*)(ws + C8_OFF);

    if (ws_size < WS_MIN) return;
    const bool use_u8 = (ws_size >= WS_FULL);

    if (use_u8)
        k_cfg_u8<<<65536, 256, 0, stream>>>(CFG1, CFG2, cfg8);

    k_pre<<<8192, 64, 0, stream>>>(LIT1, SEM1, LIT2, SEM2,
                                   d1_Win, d1_bin, d1_Wout, d1_bout, d1_gk, d1_gb,
                                   d2_Win, d2_bin, d2_Wout, d2_bout, d2_gk, d2_gb,
                                   ebuf, xproj);

    k_gru<<<64, 64, 0, stream>>>(d1_grk, d1_gb, d2_grk, d2_gb, xproj, ebuf);

    for (int it = 0; it < 5; ++it) {
        if (use_u8)
            k_msg<1><<<512, 256, 0, stream>>>((const uint8_t*)cfg8, CFG1, CFG2, ebuf, tbuf);
        else
            k_msg<0><<<512, 256, 0, stream>>>((const uint8_t*)cfg8, CFG1, CFG2, ebuf, tbuf);
        k_mlp<<<1024, 64, 0, stream>>>(tbuf, ebuf, mlpW, mlpb);
    }

    k_out<<<GBN, 64, 0, stream>>>(ebuf, wOut, bOut, outws);
    k_cos<<<32, 64, 0, stream>>>(outws, (float*)d_out);
}

// Round 3
// 1044.718 us; speedup vs baseline: 1.7213x; 1.4070x over previous
//
#include <hip/hip_runtime.h>
#include <stdint.h>
#include <math.h>

#define B_   32
#define N_   1024
#define U_   32
#define E_   64
#define LIT_ 12
#define SEM_ 16
#define GBN  64   // 2 graphs * 32 batch

typedef float f32x4 __attribute__((ext_vector_type(4)));
typedef short s16x8 __attribute__((ext_vector_type(8)));
#define MFMA_BF16(a,b,c) __builtin_amdgcn_mfma_f32_16x16x32_bf16(a,b,c,0,0,0)

// ---------------- fast-path workspace layout (bytes) ----------------
// phase1 overlay: xproj [0, 25165824) (dead after k_gru)
#define F_ET0H 0ULL
#define F_ET0L 8388608ULL
#define F_ET1H 16777216ULL
#define F_ET1L 25165824ULL
#define F_EBUF 33554432ULL
#define F_CFGB 50331648ULL     // 8388608 bit-packed cfg
#define F_OUTW 58720256ULL     // 16384
#define F_WBUF 58736640ULL     // 32768 (wT hi/lo, 2 layers)
#define F_MIN  58769408ULL

// ---------------- fallback (round-2) layout ----------------
#define O_XPROJ 0ULL
#define O_T     25165824ULL
#define O_E     41943040ULL
#define O_OW    58720256ULL
#define O_MIN   58736640ULL

__device__ __forceinline__ float rdlane(float v, int k) {
    return __int_as_float(__builtin_amdgcn_readlane(__float_as_int(v), k));
}
__device__ __forceinline__ unsigned short bf16rne(float x) {
    unsigned u = __float_as_uint(x);
    return (unsigned short)((u + 0x7FFFu + ((u >> 16) & 1u)) >> 16);
}
__device__ __forceinline__ void hilo(float x, short& h, short& l) {
    unsigned short hb = bf16rne(x);
    float hf = __uint_as_float(((unsigned)hb) << 16);
    h = (short)hb;
    l = (short)bf16rne(x - hf);
}

// ---------- literal path + GRU input projection ----------
__global__ __launch_bounds__(64) void k_pre(
    const float* __restrict__ lit1, const float* __restrict__ sem1,
    const float* __restrict__ lit2, const float* __restrict__ sem2,
    const float* __restrict__ Win1, const float* __restrict__ bin1,
    const float* __restrict__ Wout1, const float* __restrict__ bout1,
    const float* __restrict__ gk1, const float* __restrict__ gb1,
    const float* __restrict__ Win2, const float* __restrict__ bin2,
    const float* __restrict__ Wout2, const float* __restrict__ bout2,
    const float* __restrict__ gk2, const float* __restrict__ gb2,
    float* __restrict__ ebuf, float* __restrict__ xproj)
{
    __shared__ float lit_ls[LIT_];
    __shared__ float sem_ls[SEM_];
    __shared__ float mid_ls[E_];
    const int tid = threadIdx.x;
    const long long rowbase = (long long)blockIdx.x * 8;
    for (int rr = 0; rr < 8; ++rr) {
        long long row = rowbase + rr;              // (g*32+b)*1024 + n
        int g = (int)(row >> 15);
        long long nIdx = row & 32767;              // b*1024+n
        const float* lit  = g ? lit2  : lit1;
        const float* sem  = g ? sem2  : sem1;
        const float* Win  = g ? Win2  : Win1;
        const float* bin  = g ? bin2  : bin1;
        const float* Wout = g ? Wout2 : Wout1;
        const float* bout = g ? bout2 : bout1;
        const float* gk   = g ? gk2   : gk1;
        const float* gbp  = g ? gb2   : gb1;

        if (tid < LIT_) lit_ls[tid] = lit[nIdx * LIT_ + tid];
        if (tid < SEM_) sem_ls[tid] = sem[nIdx * SEM_ + tid];
        __syncthreads();

        float acc = bin[tid];
        #pragma unroll
        for (int k = 0; k < LIT_; ++k) acc += lit_ls[k] * Win[k * E_ + tid];
        mid_ls[tid] = fmaxf(acc, 0.f);
        __syncthreads();

        if (tid < U_) {
            float a = bout[tid];
            #pragma unroll
            for (int k = 0; k < E_; ++k) a += mid_ls[k] * Wout[k * U_ + tid];
            ebuf[row * E_ + tid] = fmaxf(a, 0.f);   // literal half
        }
        {
            float a = gbp[tid];
            #pragma unroll
            for (int k = 0; k < SEM_; ++k) a += sem_ls[k] * gk[k * 96 + tid];
            xproj[row * 96 + tid] = a;
        }
        if (tid < 32) {
            int j = 64 + tid;
            float a = gbp[j];
            #pragma unroll
            for (int k = 0; k < SEM_; ++k) a += sem_ls[k] * gk[k * 96 + j];
            xproj[row * 96 + j] = a;
        }
        __syncthreads();
    }
}

// ---------- GRU (blocks 0..63) + cfg bit-pack (64..4159) + W prep (4160) ----------
__global__ __launch_bounds__(64) void k_gru_cfg(
    const float* __restrict__ grk1, const float* __restrict__ gb1,
    const float* __restrict__ grk2, const float* __restrict__ gb2,
    const float* __restrict__ xproj, float* __restrict__ ebuf,
    const int* __restrict__ c1, const int* __restrict__ c2,
    uint8_t* __restrict__ cfgb,
    const float* __restrict__ mlpW, short* __restrict__ wbuf)
{
    const int tid = threadIdx.x;
    if (blockIdx.x >= 64) {
        if (blockIdx.x <= 4159) {
            // ---- bit-pack cfg: 8 int32 -> 1 byte ----
            int g = blockIdx.x - 64;                 // 0..4095
            long long gt = (long long)g * 64 + tid;  // 0..262143
            #pragma unroll 4
            for (int it = 0; it < 32; ++it) {
                long long o = gt + 262144LL * it;    // byte index 0..8388607
                const int* src = (o < 4194304LL) ? c1 : c2;
                long long oo = (o < 4194304LL) ? o : o - 4194304LL;
                const int4* p = (const int4*)(src + oo * 8);
                int4 v0 = p[0], v1 = p[1];
                unsigned bb = (unsigned)(v0.x & 1) | ((unsigned)(v0.y & 1) << 1) |
                              ((unsigned)(v0.z & 1) << 2) | ((unsigned)(v0.w & 1) << 3) |
                              ((unsigned)(v1.x & 1) << 4) | ((unsigned)(v1.y & 1) << 5) |
                              ((unsigned)(v1.z & 1) << 6) | ((unsigned)(v1.w & 1) << 7);
                cfgb[o] = (uint8_t)bb;
            }
        } else {
            // ---- wT hi/lo prep: wbuf[layer][hi/lo][out][in] ----
            for (int idx = tid; idx < 8192; idx += 64) {
                int layer = idx >> 12, rem = idx & 4095, out = rem >> 6, in = rem & 63;
                float x = mlpW[layer * 4096 + in * 64 + out];
                short h, l2; hilo(x, h, l2);
                wbuf[layer * 8192 + out * 64 + in] = h;
                wbuf[layer * 8192 + 4096 + out * 64 + in] = l2;
            }
        }
        return;
    }

    // ---- GRU: single wave per (g,b), barrier-free ----
    const int gb_i = blockIdx.x;          // 0..63
    const int g = gb_i >> 5;
    const float* grk = g ? grk2 : grk1;
    const float* gbp = g ? gb2 : gb1;
    const int l = tid;                    // 0..63
    const int j = l & 31;

    float wzr[32];                        // Wr[k][l]
    float wh[32];                         // Wr[k][64+j]
    #pragma unroll
    for (int k = 0; k < 32; ++k) {
        wzr[k] = grk[k * 96 + l];
        wh[k]  = grk[k * 96 + 64 + j];
    }
    const float brec0 = gbp[96 + l];
    const float brec1 = gbp[96 + 64 + j];

    const float* xp = xproj + (long long)gb_i * N_ * 96;
    float* eb = ebuf + (long long)gb_i * N_ * E_ + 32;

    float h = 0.f;

    auto STEP = [&](float X0, float X1, int T) {
        float a0 = brec0, a1 = 0.f, a2 = 0.f, a3 = 0.f;
        float b0 = brec1, b1 = 0.f, b2 = 0.f, b3 = 0.f;
        #pragma unroll
        for (int k = 0; k < 32; k += 4) {
            float h0 = rdlane(h, k);
            float h1 = rdlane(h, k + 1);
            float h2 = rdlane(h, k + 2);
            float h3 = rdlane(h, k + 3);
            a0 = fmaf(h0, wzr[k],     a0);  b0 = fmaf(h0, wh[k],     b0);
            a1 = fmaf(h1, wzr[k + 1], a1);  b1 = fmaf(h1, wh[k + 1], b1);
            a2 = fmaf(h2, wzr[k + 2], a2);  b2 = fmaf(h2, wh[k + 2], b2);
            a3 = fmaf(h3, wzr[k + 3], a3);  b3 = fmaf(h3, wh[k + 3], b3);
        }
        float rec0 = (a0 + a1) + (a2 + a3);
        float rec1 = (b0 + b1) + (b2 + b3);
        float s = 1.f / (1.f + __expf(-(X0 + rec0)));
        float zv = __shfl(s, j);
        float rv = __shfl(s, j + 32);
        float y  = X1 + rv * rec1;
        float e2 = __expf(2.f * y);
        float hh = 1.f - 2.f / (e2 + 1.f);
        float hn = hh + zv * (h - hh);
        h = hn;
        if (l < 32) eb[(long long)(T) * E_ + l] = fmaxf(hn, 0.f);
    };

    float x0a = xp[l],       x1a = xp[64 + j];
    float x0b = xp[96 + l],  x1b = xp[96 + 64 + j];

    for (int t = 0; t < N_; t += 2) {
        float nx0a = xp[(long long)(t + 2) * 96 + l];
        float nx1a = xp[(long long)(t + 2) * 96 + 64 + j];
        float nx0b = xp[(long long)(t + 3) * 96 + l];
        float nx1b = xp[(long long)(t + 3) * 96 + 64 + j];
        STEP(x0a, x1a, t);
        STEP(x0b, x1b, t + 1);
        x0a = nx0a; x1a = nx1a; x0b = nx0b; x1b = nx1b;
    }
}

// ---------- e (fp32, row-major) -> eT (bf16 hi/lo, [gb][64][1024]) ----------
__global__ __launch_bounds__(256) void k_etr(const float* __restrict__ ebuf,
                                             short* __restrict__ eTh,
                                             short* __restrict__ eTl)
{
    __shared__ float tls[128][68];
    const int blk = blockIdx.x, gb = blk >> 3, n0 = (blk & 7) * 128;
    const int tid = threadIdx.x;
    const float4* src = (const float4*)(ebuf + ((size_t)gb * N_ + n0) * E_);
    #pragma unroll
    for (int i = 0; i < 8; ++i) {
        int idx = tid + 256 * i;         // 2048 float4
        float4 v = src[idx];
        int row = idx >> 4, c4 = (idx & 15) << 2;
        tls[row][c4] = v.x; tls[row][c4 + 1] = v.y;
        tls[row][c4 + 2] = v.z; tls[row][c4 + 3] = v.w;
    }
    __syncthreads();
    const int w = tid >> 6, l = tid & 63;
    short* dh = eTh + ((size_t)gb << 16) + (size_t)l * 1024 + n0 + w * 32;
    short* dl = eTl + ((size_t)gb << 16) + (size_t)l * 1024 + n0 + w * 32;
    #pragma unroll
    for (int ch = 0; ch < 4; ++ch) {
        s16x8 vh, vl;
        #pragma unroll
        for (int i = 0; i < 8; ++i) {
            short hh, ll; hilo(tls[w * 32 + ch * 8 + i][l], hh, ll);
            vh[i] = hh; vl[i] = ll;
        }
        *(s16x8*)(dh + ch * 8) = vh;
        *(s16x8*)(dl + ch * 8) = vl;
    }
}

// ---------- fused message passing + 2-layer MLP + tanh residual (MFMA) ----------
template<int WET>
__global__ __launch_bounds__(256, 2) void k_msgmlp(
    const uint8_t* __restrict__ cfgb,
    const short* __restrict__ eThS, const short* __restrict__ eTlS,
    short* __restrict__ eThD, short* __restrict__ eTlD,
    float* __restrict__ ebuf,
    const short* __restrict__ wbuf, const float* __restrict__ mlpb)
{
    __shared__ float tls[128][68];
    const int blk = blockIdx.x, gb = blk >> 3, n0 = (blk & 7) * 128;
    const int tid = threadIdx.x, w = tid >> 6, l = tid & 63;
    const int lr = l & 15, lk8 = (l >> 4) * 8;

    const uint8_t* ca = cfgb + ((size_t)gb << 17) + (size_t)(n0 + w * 32 + lr) * 128 + (l >> 4);
    const short* bh = eThS + ((size_t)gb << 16) + (size_t)lr * 1024 + lk8;
    const short* bl = eTlS + ((size_t)gb << 16) + (size_t)lr * 1024 + lk8;

    f32x4 acc[2][4];
    #pragma unroll
    for (int mt = 0; mt < 2; ++mt)
        #pragma unroll
        for (int nt = 0; nt < 4; ++nt)
            acc[mt][nt] = (f32x4){0.f, 0.f, 0.f, 0.f};

    // ---- main loop: t = cfg @ e  (K = 1024, step 32) ----
    #pragma unroll 2
    for (int kk = 0; kk < 1024; kk += 32) {
        unsigned byte0 = ca[kk >> 3];
        unsigned byte1 = ca[2048 + (kk >> 3)];
        s16x8 a0, a1;
        #pragma unroll
        for (int i = 0; i < 8; ++i) {
            a0[i] = (short)(-(int)((byte0 >> i) & 1u) & 0x3F80);
            a1[i] = (short)(-(int)((byte1 >> i) & 1u) & 0x3F80);
        }
        #pragma unroll
        for (int nt = 0; nt < 4; ++nt) {
            s16x8 vh = *(const s16x8*)(bh + nt * 16384 + kk);
            s16x8 vl = *(const s16x8*)(bl + nt * 16384 + kk);
            acc[0][nt] = MFMA_BF16(a0, vh, acc[0][nt]);
            acc[0][nt] = MFMA_BF16(a0, vl, acc[0][nt]);
            acc[1][nt] = MFMA_BF16(a1, vh, acc[1][nt]);
            acc[1][nt] = MFMA_BF16(a1, vl, acc[1][nt]);
        }
    }

    // ---- t -> LDS (wave-local rows w*32..w*32+31) ----
    #pragma unroll
    for (int mt = 0; mt < 2; ++mt)
        #pragma unroll
        for (int nt = 0; nt < 4; ++nt)
            #pragma unroll
            for (int r = 0; r < 4; ++r)
                tls[w * 32 + mt * 16 + (l >> 4) * 4 + r][nt * 16 + lr] = acc[mt][nt][r];

    float b0c[4], b1c[4];
    #pragma unroll
    for (int nt = 0; nt < 4; ++nt) {
        b0c[nt] = mlpb[nt * 16 + lr];
        b1c[nt] = mlpb[64 + nt * 16 + lr];
    }

    // ================= layer 1 =================
    s16x8 ah[2][2], al[2][2];
    #pragma unroll
    for (int mt = 0; mt < 2; ++mt)
        #pragma unroll
        for (int kt = 0; kt < 2; ++kt) {
            const float* p = &tls[w * 32 + mt * 16 + lr][kt * 32 + lk8];
            #pragma unroll
            for (int i = 0; i < 8; ++i) { short hh, ll; hilo(p[i], hh, ll); ah[mt][kt][i] = hh; al[mt][kt][i] = ll; }
        }
    {
        f32x4 acc1[2][4];
        #pragma unroll
        for (int mt = 0; mt < 2; ++mt)
            #pragma unroll
            for (int nt = 0; nt < 4; ++nt)
                acc1[mt][nt] = (f32x4){b0c[nt], b0c[nt], b0c[nt], b0c[nt]};
        #pragma unroll
        for (int nt = 0; nt < 4; ++nt)
            #pragma unroll
            for (int kt = 0; kt < 2; ++kt) {
                s16x8 wth = *(const s16x8*)(wbuf + (nt * 16 + lr) * 64 + kt * 32 + lk8);
                s16x8 wtl = *(const s16x8*)(wbuf + 4096 + (nt * 16 + lr) * 64 + kt * 32 + lk8);
                #pragma unroll
                for (int mt = 0; mt < 2; ++mt) {
                    acc1[mt][nt] = MFMA_BF16(ah[mt][kt], wth, acc1[mt][nt]);
                    acc1[mt][nt] = MFMA_BF16(ah[mt][kt], wtl, acc1[mt][nt]);
                    acc1[mt][nt] = MFMA_BF16(al[mt][kt], wth, acc1[mt][nt]);
                }
            }
        // relu -> LDS (wave-local; in-wave DS ordering keeps RAW/WAR safe)
        #pragma unroll
        for (int mt = 0; mt < 2; ++mt)
            #pragma unroll
            for (int nt = 0; nt < 4; ++nt)
                #pragma unroll
                for (int r = 0; r < 4; ++r)
                    tls[w * 32 + mt * 16 + (l >> 4) * 4 + r][nt * 16 + lr] = fmaxf(acc1[mt][nt][r], 0.f);
    }

    // ================= layer 2 =================
    #pragma unroll
    for (int mt = 0; mt < 2; ++mt)
        #pragma unroll
        for (int kt = 0; kt < 2; ++kt) {
            const float* p = &tls[w * 32 + mt * 16 + lr][kt * 32 + lk8];
            #pragma unroll
            for (int i = 0; i < 8; ++i) { short hh, ll; hilo(p[i], hh, ll); ah[mt][kt][i] = hh; al[mt][kt][i] = ll; }
        }
    f32x4 acc2[2][4];
    #pragma unroll
    for (int mt = 0; mt < 2; ++mt)
        #pragma unroll
        for (int nt = 0; nt < 4; ++nt)
            acc2[mt][nt] = (f32x4){b1c[nt], b1c[nt], b1c[nt], b1c[nt]};
    #pragma unroll
    for (int nt = 0; nt < 4; ++nt)
        #pragma unroll
        for (int kt = 0; kt < 2; ++kt) {
            s16x8 wth = *(const s16x8*)(wbuf + 8192 + (nt * 16 + lr) * 64 + kt * 32 + lk8);
            s16x8 wtl = *(const s16x8*)(wbuf + 8192 + 4096 + (nt * 16 + lr) * 64 + kt * 32 + lk8);
            #pragma unroll
            for (int mt = 0; mt < 2; ++mt) {
                acc2[mt][nt] = MFMA_BF16(ah[mt][kt], wth, acc2[mt][nt]);
                acc2[mt][nt] = MFMA_BF16(ah[mt][kt], wtl, acc2[mt][nt]);
                acc2[mt][nt] = MFMA_BF16(al[mt][kt], wth, acc2[mt][nt]);
            }
        }

    // ---- e_new = tanh(e_old + relu(acc2)); write ebuf (+ LDS for transpose) ----
    float* eb = ebuf + ((size_t)gb * N_ + n0) * E_;
    #pragma unroll
    for (int mt = 0; mt < 2; ++mt)
        #pragma unroll
        for (int nt = 0; nt < 4; ++nt)
            #pragma unroll
            for (int r = 0; r < 4; ++r) {
                int row = w * 32 + mt * 16 + (l >> 4) * 4 + r;
                int col = nt * 16 + lr;
                float t2 = fmaxf(acc2[mt][nt][r], 0.f);
                float y = eb[(size_t)row * E_ + col] + t2;
                float e2 = __expf(2.f * y);
                float en = 1.f - 2.f / (e2 + 1.f);
                eb[(size_t)row * E_ + col] = en;
                if (WET) tls[row][col] = en;
            }

    if (WET) {
        // transposed bf16 hi/lo write-out (wave-local rows)
        short* dh = eThD + ((size_t)gb << 16) + (size_t)l * 1024 + n0 + w * 32;
        short* dl = eTlD + ((size_t)gb << 16) + (size_t)l * 1024 + n0 + w * 32;
        #pragma unroll
        for (int ch = 0; ch < 4; ++ch) {
            s16x8 vh, vl;
            #pragma unroll
            for (int i = 0; i < 8; ++i) {
                short hh, ll; hilo(tls[w * 32 + ch * 8 + i][l], hh, ll);
                vh[i] = hh; vl[i] = ll;
            }
            *(s16x8*)(dh + ch * 8) = vh;
            *(s16x8*)(dl + ch * 8) = vl;
        }
    }
}

// ---------- fallback (round-2) message passing ----------
__global__ __launch_bounds__(256) void k_msg_fb(
    const int* __restrict__ cfgi1, const int* __restrict__ cfgi2,
    const float* __restrict__ ebuf, float* __restrict__ tbuf)
{
    __shared__ float cfgf[128][65];
    __shared__ float els[64][64];
    const int blk = blockIdx.x;
    const int gb_i = blk >> 3;
    const int rg = blk & 7;
    const int g = gb_i >> 5;
    const int b = gb_i & 31;
    const int n0 = rg * 128;
    const int tid = threadIdx.x;
    const int tx = tid & 7, ty = tid >> 3;

    float acc[4][8];
    #pragma unroll
    for (int i = 0; i < 4; ++i)
        #pragma unroll
        for (int c = 0; c < 8; ++c) acc[i][c] = 0.f;

    const float* ebase = ebuf + (long long)gb_i * N_ * E_;
    const int row = tid >> 1, half = tid & 1;

    for (int m0 = 0; m0 < N_; m0 += 64) {
        {
            const float4* src = (const float4*)(ebase + (long long)m0 * E_);
            float4* dst = (float4*)(&els[0][0]);
            #pragma unroll
            for (int k = 0; k < 4; ++k) dst[tid + 256 * k] = src[tid + 256 * k];
        }
        {
            const int* cp = (g ? cfgi2 : cfgi1) + ((long long)b * N_ + n0 + row) * N_ + m0 + half * 32;
            #pragma unroll
            for (int q = 0; q < 8; ++q) {
                int4 v = ((const int4*)cp)[q];
                cfgf[row][half * 32 + q * 4 + 0] = (float)v.x;
                cfgf[row][half * 32 + q * 4 + 1] = (float)v.y;
                cfgf[row][half * 32 + q * 4 + 2] = (float)v.z;
                cfgf[row][half * 32 + q * 4 + 3] = (float)v.w;
            }
        }
        __syncthreads();

        #pragma unroll 4
        for (int mm = 0; mm < 64; ++mm) {
            float4 e0 = *(const float4*)&els[mm][tx * 8];
            float4 e1 = *(const float4*)&els[mm][tx * 8 + 4];
            #pragma unroll
            for (int i = 0; i < 4; ++i) {
                float c = cfgf[ty + 32 * i][mm];
                acc[i][0] += c * e0.x; acc[i][1] += c * e0.y;
                acc[i][2] += c * e0.z; acc[i][3] += c * e0.w;
                acc[i][4] += c * e1.x; acc[i][5] += c * e1.y;
                acc[i][6] += c * e1.z; acc[i][7] += c * e1.w;
            }
        }
        __syncthreads();
    }

    float* tb = tbuf + (long long)gb_i * N_ * E_;
    #pragma unroll
    for (int i = 0; i < 4; ++i) {
        int r = n0 + ty + 32 * i;
        float4 o0 = {acc[i][0], acc[i][1], acc[i][2], acc[i][3]};
        float4 o1 = {acc[i][4], acc[i][5], acc[i][6], acc[i][7]};
        *(float4*)&tb[(long long)r * E_ + tx * 8] = o0;
        *(float4*)&tb[(long long)r * E_ + tx * 8 + 4] = o1;
    }
}

// ---------- fallback MLP ----------
__global__ __launch_bounds__(64) void k_mlp_fb(
    const float* __restrict__ tbuf, float* __restrict__ ebuf,
    const float* __restrict__ mlpW, const float* __restrict__ mlpb)
{
    __shared__ float tls[64][65];
    __shared__ float mls[64][65];
    const int tid = threadIdx.x;
    const long long r0 = (long long)blockIdx.x * 64;

    {
        const float4* src = (const float4*)(tbuf + r0 * E_);
        #pragma unroll
        for (int i = 0; i < 16; ++i) {
            int f4 = tid + 64 * i;
            float4 v = src[f4];
            int row = f4 >> 4, col = (f4 & 15) << 2;
            tls[row][col] = v.x; tls[row][col + 1] = v.y;
            tls[row][col + 2] = v.z; tls[row][col + 3] = v.w;
        }
    }
    __syncthreads();

    for (int dc = 0; dc < 8; ++dc) {
        float a[8];
        #pragma unroll
        for (int c = 0; c < 8; ++c) a[c] = mlpb[dc * 8 + c];
        #pragma unroll 8
        for (int k = 0; k < 64; ++k) {
            float tv = tls[tid][k];
            #pragma unroll
            for (int c = 0; c < 8; ++c) a[c] += tv * mlpW[k * 64 + dc * 8 + c];
        }
        #pragma unroll
        for (int c = 0; c < 8; ++c) mls[tid][dc * 8 + c] = fmaxf(a[c], 0.f);
    }
    for (int dc = 0; dc < 8; ++dc) {
        float a[8];
        #pragma unroll
        for (int c = 0; c < 8; ++c) a[c] = mlpb[64 + dc * 8 + c];
        #pragma unroll 8
        for (int k = 0; k < 64; ++k) {
            float tv = mls[tid][k];
            #pragma unroll
            for (int c = 0; c < 8; ++c) a[c] += tv * mlpW[4096 + k * 64 + dc * 8 + c];
        }
        #pragma unroll
        for (int c = 0; c < 8; ++c) tls[tid][dc * 8 + c] = fmaxf(a[c], 0.f);
    }
    __syncthreads();

    {
        float4* eb = (float4*)(ebuf + r0 * E_);
        #pragma unroll
        for (int i = 0; i < 16; ++i) {
            int f4 = tid + 64 * i;
            int row = f4 >> 4, col = (f4 & 15) << 2;
            float4 ev = eb[f4];
            float4 o;
            o.x = tanhf(ev.x + tls[row][col]);
            o.y = tanhf(ev.y + tls[row][col + 1]);
            o.z = tanhf(ev.z + tls[row][col + 2]);
            o.w = tanhf(ev.w + tls[row][col + 3]);
            eb[f4] = o;
        }
    }
}

// ---------- node-sum + output projection ----------
__global__ __launch_bounds__(64) void k_out(const float* __restrict__ ebuf,
                                            const float* __restrict__ wOut,
                                            const float* __restrict__ bOut,
                                            float* __restrict__ outws)
{
    __shared__ float mid[E_];
    const int gb_i = blockIdx.x;
    const int tid = threadIdx.x;
    const float* eb = ebuf + (long long)gb_i * N_ * E_;
    float s = 0.f;
    for (int n = 0; n < N_; ++n) s += eb[(long long)n * E_ + tid];
    mid[tid] = s;
    __syncthreads();
    float a = bOut[tid];
    #pragma unroll 8
    for (int k = 0; k < E_; ++k) a += mid[k] * wOut[k * E_ + tid];
    outws[gb_i * E_ + tid] = a;
}

// ---------- cosine -> label ----------
__global__ __launch_bounds__(64) void k_cos(const float* __restrict__ outws,
                                            float* __restrict__ dout)
{
    const int b = blockIdx.x, d = threadIdx.x;
    float a = outws[b * E_ + d];
    float c = outws[(32 + b) * E_ + d];
    float s1 = a * a, s2 = c * c, s3 = a * c;
    #pragma unroll
    for (int m = 32; m > 0; m >>= 1) {
        s1 += __shfl_xor(s1, m);
        s2 += __shfl_xor(s2, m);
        s3 += __shfl_xor(s3, m);
    }
    if (d == 0) {
        float n1 = sqrtf(fmaxf(s1, 1e-12f));
        float n2 = sqrtf(fmaxf(s2, 1e-12f));
        dout[b] = 0.5f * (s3 / (n1 * n2) + 1.0f);
    }
}

extern "C" void kernel_launch(void* const* d_in, const int* in_sizes, int n_in,
                              void* d_out, int out_size, void* d_ws, size_t ws_size,
                              hipStream_t stream) {
    const int*   CFG1 = (const int*)d_in[0];
    const float* LIT1 = (const float*)d_in[2];
    const float* SEM1 = (const float*)d_in[3];
    const int*   CFG2 = (const int*)d_in[4];
    const float* LIT2 = (const float*)d_in[6];
    const float* SEM2 = (const float*)d_in[7];
    const float* d1_Win  = (const float*)d_in[8];
    const float* d1_bin  = (const float*)d_in[9];
    const float* d1_Wout = (const float*)d_in[10];
    const float* d1_bout = (const float*)d_in[11];
    const float* d1_gk   = (const float*)d_in[12];
    const float* d1_grk  = (const float*)d_in[13];
    const float* d1_gb   = (const float*)d_in[14];
    const float* d2_Win  = (const float*)d_in[15];
    const float* d2_bin  = (const float*)d_in[16];
    const float* d2_Wout = (const float*)d_in[17];
    const float* d2_bout = (const float*)d_in[18];
    const float* d2_gk   = (const float*)d_in[19];
    const float* d2_grk  = (const float*)d_in[20];
    const float* d2_gb   = (const float*)d_in[21];
    const float* mlpW = (const float*)d_in[22];
    const float* mlpb = (const float*)d_in[23];
    const float* wOut = (const float*)d_in[24];
    const float* bOut = (const float*)d_in[25];

    char* ws = (char*)d_ws;

    if (ws_size >= F_MIN) {
        float*   xproj = (float*)(ws + 0);            // phase-1 overlay
        short*   eT0h  = (short*)(ws + F_ET0H);
        short*   eT0l  = (short*)(ws + F_ET0L);
        short*   eT1h  = (short*)(ws + F_ET1H);
        short*   eT1l  = (short*)(ws + F_ET1L);
        float*   ebuf  = (float*)(ws + F_EBUF);
        uint8_t* cfgb  = (uint8_t*)(ws + F_CFGB);
        float*   outws = (float*)(ws + F_OUTW);
        short*   wbuf  = (short*)(ws + F_WBUF);

        k_pre<<<8192, 64, 0, stream>>>(LIT1, SEM1, LIT2, SEM2,
                                       d1_Win, d1_bin, d1_Wout, d1_bout, d1_gk, d1_gb,
                                       d2_Win, d2_bin, d2_Wout, d2_bout, d2_gk, d2_gb,
                                       ebuf, xproj);

        k_gru_cfg<<<4161, 64, 0, stream>>>(d1_grk, d1_gb, d2_grk, d2_gb, xproj, ebuf,
                                           CFG1, CFG2, cfgb, mlpW, wbuf);

        k_etr<<<512, 256, 0, stream>>>(ebuf, eT0h, eT0l);

        for (int it = 0; it < 5; ++it) {
            short* sh = (it & 1) ? eT1h : eT0h;
            short* sl = (it & 1) ? eT1l : eT0l;
            short* dh = (it & 1) ? eT0h : eT1h;
            short* dl = (it & 1) ? eT0l : eT1l;
            if (it < 4)
                k_msgmlp<1><<<512, 256, 0, stream>>>(cfgb, sh, sl, dh, dl, ebuf, wbuf, mlpb);
            else
                k_msgmlp<0><<<512, 256, 0, stream>>>(cfgb, sh, sl, dh, dl, ebuf, wbuf, mlpb);
        }

        k_out<<<GBN, 64, 0, stream>>>(ebuf, wOut, bOut, outws);
        k_cos<<<32, 64, 0, stream>>>(outws, (float*)d_out);
    } else if (ws_size >= O_MIN) {
        // -------- fallback: round-2 structure --------
        float* xproj = (float*)(ws + O_XPROJ);
        float* tbuf  = (float*)(ws + O_T);
        float* ebuf  = (float*)(ws + O_E);
        float* outws = (float*)(ws + O_OW);

        k_pre<<<8192, 64, 0, stream>>>(LIT1, SEM1, LIT2, SEM2,
                                       d1_Win, d1_bin, d1_Wout, d1_bout, d1_gk, d1_gb,
                                       d2_Win, d2_bin, d2_Wout, d2_bout, d2_gk, d2_gb,
                                       ebuf, xproj);

        k_gru_cfg<<<64, 64, 0, stream>>>(d1_grk, d1_gb, d2_grk, d2_gb, xproj, ebuf,
                                         CFG1, CFG2, (uint8_t*)ws, mlpW, (short*)ws);

        for (int it = 0; it < 5; ++it) {
            k_msg_fb<<<512, 256, 0, stream>>>(CFG1, CFG2, ebuf, tbuf);
            k_mlp_fb<<<1024, 64, 0, stream>>>(tbuf, ebuf, mlpW, mlpb);
        }

        k_out<<<GBN, 64, 0, stream>>>(ebuf, wOut, bOut, outws);
        k_cos<<<32, 64, 0, stream>>>(outws, (float*)d_out);
    }
}